// Round 12
// baseline (216.922 us; speedup 1.0000x reference)
//
#include <hip/hip_runtime.h>

#define F 4096          // feature dim (S_DIM == HID == A_DIM)
#define NE 44
#define NN 14
#define KB 8            // k-split factor
#define KC 512          // k-chunk width per block
#define TROWS 32        // W-tile rows (tile = 32x512x4B = 64 KB)
#define NTILE 4         // tiles per block (block covers 128 rows)
#define YPART 57344     // 14*4096, one partial Y buffer
#define H1SZ 180224     // 44*4096

// deterministic edge list from reference _edge_list()
__device__ constexpr int SRC[NE] = {
    0,1,2,3,4,5,6,7,8,9,10,11,12,13,          // fwd ring
    1,2,3,4,5,6,7,8,9,10,11,12,13,0,          // rev ring
    0,1,2,3,4,5,6,7,8,9,10,11,12,13,          // skip-2 ring
    0,7};
__device__ constexpr int DST[NE] = {
    1,2,3,4,5,6,7,8,9,10,11,12,13,0,
    0,1,2,3,4,5,6,7,8,9,10,11,12,13,
    2,3,4,5,6,7,8,9,10,11,12,13,0,1,
    7,0};
// deg: 3 everywhere except nodes 0 and 7 (4)
__device__ constexpr float INVDEG[NN] = {
    0.25f, 1.f/3.f, 1.f/3.f, 1.f/3.f, 1.f/3.f, 1.f/3.f, 1.f/3.f,
    0.25f, 1.f/3.f, 1.f/3.f, 1.f/3.f, 1.f/3.f, 1.f/3.f, 1.f/3.f};

// async global->LDS, 16 B per lane; LDS dest = uniform base + lane*16 (linear)
__device__ __forceinline__ void gload16(const float* g, float* l) {
    __builtin_amdgcn_global_load_lds(
        (const __attribute__((address_space(1))) void*)g,
        (__attribute__((address_space(3))) void*)l, 16, 0, 0);
}

// ---------------- prep: A = node2(edge_features) -------------------------
__global__ __launch_bounds__(256) void prep_x_k(const float* __restrict__ x,
                                                float* __restrict__ Aout) {
    int f = blockIdx.x * 256 + threadIdx.x;   // 16 blocks cover 4096
    float s[NN];
#pragma unroll
    for (int n = 0; n < NN; ++n) s[n] = 0.f;
#pragma unroll
    for (int e = 0; e < NE; ++e) s[DST[e]] += x[e * F + f];
    float node[NN];
#pragma unroll
    for (int n = 0; n < NN; ++n) node[n] = s[n] * INVDEG[n];
    float n2[NN];
#pragma unroll
    for (int n = 0; n < NN; ++n) n2[n] = 0.f;
#pragma unroll
    for (int e = 0; e < NE; ++e) n2[DST[e]] += node[SRC[e]];
#pragma unroll
    for (int m = 0; m < NN; ++m) Aout[m * F + f] = n2[m];
}

// inner layers: edge feat = leaky_relu(0.5*(Y[src]+Y[dst]) + b), Y = sum of KB partials
__device__ __forceinline__ void prep_col(const float* __restrict__ Yp,
                                         const float* __restrict__ b,
                                         float* __restrict__ Aout, int f) {
    float y[NN];
#pragma unroll
    for (int m = 0; m < NN; ++m) {
        float s = 0.f;
#pragma unroll
        for (int kb = 0; kb < KB; ++kb) s += Yp[kb * YPART + m * F + f];
        y[m] = s;
    }
    float bias = b[f];
    float s[NN];
#pragma unroll
    for (int n = 0; n < NN; ++n) s[n] = 0.f;
#pragma unroll
    for (int e = 0; e < NE; ++e) {
        float eh = 0.5f * (y[SRC[e]] + y[DST[e]]) + bias;
        eh = eh > 0.f ? eh : 0.01f * eh;      // leaky_relu(0.01)
        s[DST[e]] += eh;
    }
    float node[NN];
#pragma unroll
    for (int n = 0; n < NN; ++n) node[n] = s[n] * INVDEG[n];
    float n2[NN];
#pragma unroll
    for (int n = 0; n < NN; ++n) n2[n] = 0.f;
#pragma unroll
    for (int e = 0; e < NE; ++e) n2[DST[e]] += node[SRC[e]];
#pragma unroll
    for (int m = 0; m < NN; ++m) Aout[m * F + f] = n2[m];
}

__global__ __launch_bounds__(256) void prep2_k(const float* __restrict__ Yp1,
                                               const float* __restrict__ b1,
                                               float* __restrict__ A1,
                                               const float* __restrict__ Yp2,
                                               const float* __restrict__ b2,
                                               float* __restrict__ A2) {
    int bx = blockIdx.x;
    if (bx < 16) {
        prep_col(Yp1, b1, A1, bx * 256 + threadIdx.x);
    } else {
        prep_col(Yp2, b2, A2, (bx - 16) * 256 + threadIdx.x);
    }
}

// ---------------- GEMM: Y[m][n] = sum_k A[m][k] * W[n][k] ----------------
// Phase-split, T3-minimal 2-phase: W streamed through a double-buffered
// 64 KB LDS tile via global_load_lds (zero-VGPR, unbounded depth -> copy
// phase behaves like the 6.3 TB/s copy ubench). Stage tile t+1 async ->
// compute tile t from LDS -> one barrier per tile (its vmcnt(0) drain
// completes tile t+1). A chunk (14x512, 28 KB) staged once.
// Block = 128 rows x KC=512: 4 tiles of 32 rows. Lane = (rowgroup
// tid>>5 -> 4 rows, kslice tid&31). acc[4][14]; A reads broadcast
// across the 32-lane groups (free), reused 4x across rows.
// LDS 156 KB -> 1 block/CU; per branch 32 nb x 8 kb = 256 blocks.
__global__ __launch_bounds__(256, 1) void gemm2_k(const float* __restrict__ A1,
                                                  const float* __restrict__ W1,
                                                  float* __restrict__ Y1,
                                                  const float* __restrict__ A2,
                                                  const float* __restrict__ W2,
                                                  float* __restrict__ Y2,
                                                  int half) {
    __shared__ float Alds[NN * KC];         // 28672 B
    __shared__ float Wlds[2][TROWS * KC];   // 2 x 65536 B (total 159744 B)
    int bx = blockIdx.x;
    const float* A = A1; const float* W = W1; float* Y = Y1;
    if (bx >= half) { A = A2; W = W2; Y = Y2; bx -= half; }
    const int kb = bx & (KB - 1);     // k chunk (512 wide)
    const int nb = bx >> 3;           // 32 row-blocks of 128
    const int tid = threadIdx.x;
    const int rg  = tid >> 5;         // rowgroup 0..7 (4 rows each)
    const int ksl = tid & 31;         // kslice 0..31 (float4 each)
    const int k0  = kb * KC;
    const int brow0 = nb * 128;       // block's first W row

    // ---- prologue: stage A chunk (7x) + W tile 0 (16x), one drain ----
#pragma unroll
    for (int i = 0; i < 7; ++i) {
        int idx = i * 256 + tid;            // float4 index in A chunk
        gload16(A + (idx >> 7) * F + k0 + (idx & 127) * 4, &Alds[idx * 4]);
    }
#pragma unroll
    for (int i = 0; i < 16; ++i) {
        int idx = i * 256 + tid;            // float4 index in W tile
        gload16(W + (size_t)(brow0 + (idx >> 7)) * F + k0 + (idx & 127) * 4,
                &Wlds[0][idx * 4]);
    }
    __syncthreads();                        // vmcnt(0): A + tile0 ready

    for (int t = 0; t < NTILE; ++t) {
        const int cur = t & 1;
        // stage next tile (async; lands by the barrier below)
        if (t + 1 < NTILE) {
            const int trow = brow0 + (t + 1) * TROWS;
#pragma unroll
            for (int i = 0; i < 16; ++i) {
                int idx = i * 256 + tid;
                gload16(W + (size_t)(trow + (idx >> 7)) * F + k0 + (idx & 127) * 4,
                        &Wlds[cur ^ 1][idx * 4]);
            }
        }
        // compute tile t from LDS
        float acc[4][NN];
#pragma unroll
        for (int r = 0; r < 4; ++r)
#pragma unroll
            for (int m = 0; m < NN; ++m) acc[r][m] = 0.f;
#pragma unroll
        for (int ks = 0; ks < 4; ++ks) {        // 4 ksteps x 128 floats
            const int kq = ks * 128 + ksl * 4;
            float4 a[NN];
#pragma unroll
            for (int m = 0; m < NN; ++m)
                a[m] = *(const float4*)&Alds[m * KC + kq];
#pragma unroll
            for (int r = 0; r < 4; ++r) {
                float4 wq = *(const float4*)&Wlds[cur][(rg * 4 + r) * KC + kq];
#pragma unroll
                for (int m = 0; m < NN; ++m)
                    acc[r][m] += wq.x * a[m].x + wq.y * a[m].y +
                                 wq.z * a[m].z + wq.w * a[m].w;
            }
        }
        // 5-level butterfly over the 32 kslices (stays within 32-lane group)
#pragma unroll
        for (int r = 0; r < 4; ++r)
#pragma unroll
            for (int m = 0; m < NN; ++m) {
                float v = acc[r][m];
                v += __shfl_xor(v, 1);
                v += __shfl_xor(v, 2);
                v += __shfl_xor(v, 4);
                v += __shfl_xor(v, 8);
                v += __shfl_xor(v, 16);
                acc[r][m] = v;
            }
        if (ksl == 0) {
            const int row0 = brow0 + t * TROWS + rg * 4;
#pragma unroll
            for (int r = 0; r < 4; ++r)
#pragma unroll
                for (int m = 0; m < NN; ++m)
                    Y[kb * YPART + m * F + row0 + r] = acc[r][m];
        }
        if (t + 1 < NTILE) __syncthreads();  // drain: next tile staged
    }
}

// ---------------- final: h1 edge expansion + h2 tiny GEMV ----------------
__global__ __launch_bounds__(256) void final_k(const float* __restrict__ Ypa5,
                                               const float* __restrict__ ba5,
                                               const float* __restrict__ Av2,
                                               const float* __restrict__ Wv5,
                                               const float* __restrict__ bv5,
                                               float* __restrict__ out) {
    __shared__ float red[NN][257];
    if (blockIdx.x < 176) {
        int idx4 = (blockIdx.x * 256 + threadIdx.x) * 4;  // 44*4096 elements
        int e = idx4 >> 12, f = idx4 & 4095;
        int se = SRC[e], de = DST[e];
        float4 ys = make_float4(0.f, 0.f, 0.f, 0.f);
        float4 yd = make_float4(0.f, 0.f, 0.f, 0.f);
#pragma unroll
        for (int kb = 0; kb < KB; ++kb) {
            float4 s = *(const float4*)(Ypa5 + kb * YPART + se * F + f);
            float4 d = *(const float4*)(Ypa5 + kb * YPART + de * F + f);
            ys.x += s.x; ys.y += s.y; ys.z += s.z; ys.w += s.w;
            yd.x += d.x; yd.y += d.y; yd.z += d.z; yd.w += d.w;
        }
        float4 bb = *(const float4*)(ba5 + f);
        float4 o;
        o.x = 0.5f * (ys.x + yd.x) + bb.x;
        o.y = 0.5f * (ys.y + yd.y) + bb.y;
        o.z = 0.5f * (ys.z + yd.z) + bb.z;
        o.w = 0.5f * (ys.w + yd.w) + bb.w;
        *(float4*)(out + idx4) = o;
    } else {
        // y[n] = dot(Av2[n], Wv5); h2[e] = 0.5*(y[src]+y[dst]) + bv5
        int t = threadIdx.x;
        float acc[NN];
#pragma unroll
        for (int m = 0; m < NN; ++m) acc[m] = 0.f;
        for (int f = t; f < F; f += 256) {
            float wv = Wv5[f];
#pragma unroll
            for (int m = 0; m < NN; ++m) acc[m] += Av2[m * F + f] * wv;
        }
#pragma unroll
        for (int m = 0; m < NN; ++m) red[m][t] = acc[m];
        __syncthreads();
        for (int s = 128; s > 0; s >>= 1) {
            if (t < s) {
#pragma unroll
                for (int m = 0; m < NN; ++m) red[m][t] += red[m][t + s];
            }
            __syncthreads();
        }
        if (t < NE) {
            float ys = red[SRC[t]][0], yd = red[DST[t]][0];
            out[H1SZ + t] = 0.5f * (ys + yd) + bv5[0];
        }
    }
}

extern "C" void kernel_launch(void* const* d_in, const int* in_sizes, int n_in,
                              void* d_out, int out_size, void* d_ws, size_t ws_size,
                              hipStream_t stream) {
    const float* x   = (const float*)d_in[0];
    const float* Wa1 = (const float*)d_in[3];
    const float* ba1 = (const float*)d_in[4];
    const float* Wa2 = (const float*)d_in[5];
    const float* ba2 = (const float*)d_in[6];
    const float* Wa5 = (const float*)d_in[7];
    const float* ba5 = (const float*)d_in[8];
    const float* Wv1 = (const float*)d_in[9];
    const float* bv1 = (const float*)d_in[10];
    const float* Wv2 = (const float*)d_in[11];
    const float* bv2 = (const float*)d_in[12];
    const float* Wv5 = (const float*)d_in[13];
    const float* bv5 = (const float*)d_in[14];
    float* out = (float*)d_out;

    float* ws  = (float*)d_ws;
    float* Ax  = ws;                   // 57344
    float* Aa  = ws + 57344;           // 57344
    float* Av  = ws + 114688;          // 57344
    float* Ypa = ws + 172032;          // KB*57344 = 458752
    float* Ypv = ws + 630784;          // KB*57344 = 458752 (total ~4.4 MB)

    prep_x_k<<<16,  256, 0, stream>>>(x, Ax);
    gemm2_k <<<512, 256, 0, stream>>>(Ax, Wa1, Ypa, Ax, Wv1, Ypv, 256);
    prep2_k <<<32,  256, 0, stream>>>(Ypa, ba1, Aa, Ypv, bv1, Av);
    gemm2_k <<<512, 256, 0, stream>>>(Aa, Wa2, Ypa, Av, Wv2, Ypv, 256);
    prep2_k <<<32,  256, 0, stream>>>(Ypa, ba2, Aa, Ypv, bv2, Av);
    gemm2_k <<<256, 256, 0, stream>>>(Aa, Wa5, Ypa, Aa, Wa5, Ypa, 256);
    final_k <<<177, 256, 0, stream>>>(Ypa, ba5, Av, Wv5, bv5, out);
}

// Round 13
// 152.284 us; speedup vs baseline: 1.4245x; 1.4245x over previous
//
#include <hip/hip_runtime.h>

#define F 4096          // feature dim (S_DIM == HID == A_DIM)
#define NE 44
#define NN 14
#define KB 16           // k-split factor
#define KC 256          // k-chunk width per block
#define KT 32           // k per tile (tile = 256 rows x 32 k x 4B = 32 KB)
#define NT 8            // tiles per block (KC/KT)
#define YPART 57344     // 14*4096, one partial Y buffer
#define H1SZ 180224     // 44*4096

// deterministic edge list from reference _edge_list()
__device__ constexpr int SRC[NE] = {
    0,1,2,3,4,5,6,7,8,9,10,11,12,13,          // fwd ring
    1,2,3,4,5,6,7,8,9,10,11,12,13,0,          // rev ring
    0,1,2,3,4,5,6,7,8,9,10,11,12,13,          // skip-2 ring
    0,7};
__device__ constexpr int DST[NE] = {
    1,2,3,4,5,6,7,8,9,10,11,12,13,0,
    0,1,2,3,4,5,6,7,8,9,10,11,12,13,
    2,3,4,5,6,7,8,9,10,11,12,13,0,1,
    7,0};
// deg: 3 everywhere except nodes 0 and 7 (4)
__device__ constexpr float INVDEG[NN] = {
    0.25f, 1.f/3.f, 1.f/3.f, 1.f/3.f, 1.f/3.f, 1.f/3.f, 1.f/3.f,
    0.25f, 1.f/3.f, 1.f/3.f, 1.f/3.f, 1.f/3.f, 1.f/3.f, 1.f/3.f};

// async global->LDS, 16 B per lane; LDS dest = uniform base + lane*16 (linear)
__device__ __forceinline__ void gload16(const float* g, float* l) {
    __builtin_amdgcn_global_load_lds(
        (const __attribute__((address_space(1))) void*)g,
        (__attribute__((address_space(3))) void*)l, 16, 0, 0);
}

// ---------------- prep: A = node2(edge_features) -------------------------
__global__ __launch_bounds__(256) void prep_x_k(const float* __restrict__ x,
                                                float* __restrict__ Aout) {
    int f = blockIdx.x * 256 + threadIdx.x;   // 16 blocks cover 4096
    float s[NN];
#pragma unroll
    for (int n = 0; n < NN; ++n) s[n] = 0.f;
#pragma unroll
    for (int e = 0; e < NE; ++e) s[DST[e]] += x[e * F + f];
    float node[NN];
#pragma unroll
    for (int n = 0; n < NN; ++n) node[n] = s[n] * INVDEG[n];
    float n2[NN];
#pragma unroll
    for (int n = 0; n < NN; ++n) n2[n] = 0.f;
#pragma unroll
    for (int e = 0; e < NE; ++e) n2[DST[e]] += node[SRC[e]];
#pragma unroll
    for (int m = 0; m < NN; ++m) Aout[m * F + f] = n2[m];
}

// inner layers: edge feat = leaky_relu(0.5*(Y[src]+Y[dst]) + b), Y = sum of KB partials
__device__ __forceinline__ void prep_col(const float* __restrict__ Yp,
                                         const float* __restrict__ b,
                                         float* __restrict__ Aout, int f) {
    float y[NN];
#pragma unroll
    for (int m = 0; m < NN; ++m) {
        float s = 0.f;
#pragma unroll
        for (int kb = 0; kb < KB; ++kb) s += Yp[kb * YPART + m * F + f];
        y[m] = s;
    }
    float bias = b[f];
    float s[NN];
#pragma unroll
    for (int n = 0; n < NN; ++n) s[n] = 0.f;
#pragma unroll
    for (int e = 0; e < NE; ++e) {
        float eh = 0.5f * (y[SRC[e]] + y[DST[e]]) + bias;
        eh = eh > 0.f ? eh : 0.01f * eh;      // leaky_relu(0.01)
        s[DST[e]] += eh;
    }
    float node[NN];
#pragma unroll
    for (int n = 0; n < NN; ++n) node[n] = s[n] * INVDEG[n];
    float n2[NN];
#pragma unroll
    for (int n = 0; n < NN; ++n) n2[n] = 0.f;
#pragma unroll
    for (int e = 0; e < NE; ++e) n2[DST[e]] += node[SRC[e]];
#pragma unroll
    for (int m = 0; m < NN; ++m) Aout[m * F + f] = n2[m];
}

__global__ __launch_bounds__(256) void prep2_k(const float* __restrict__ Yp1,
                                               const float* __restrict__ b1,
                                               float* __restrict__ A1,
                                               const float* __restrict__ Yp2,
                                               const float* __restrict__ b2,
                                               float* __restrict__ A2) {
    int bx = blockIdx.x;
    if (bx < 16) {
        prep_col(Yp1, b1, A1, bx * 256 + threadIdx.x);
    } else {
        prep_col(Yp2, b2, A2, (bx - 16) * 256 + threadIdx.x);
    }
}

// ---------------- GEMM: Y[m][n] = sum_k A[m][k] * W[n][k] ----------------
// 2-phase global_load_lds pipeline, rebuilt geometry vs R12:
//  - lane == W row (256 rows/block): acc[14] scalars, NO cross-lane
//    reduction, coalesced stores.
//  - W tile 256x32 (32 KB) double-buffered; XOR-swizzled storage
//    (phys granule = row*8 + (ks^(row&7))) with PRE-SWIZZLED global source
//    (rule #21) -> conflict-free ds_read_b128 at data-path rate.
//  - A chunk 14x256 (14 KB) staged once; uniform (broadcast) reads.
//  - LDS 78 KB -> 2 blocks/CU: one computes while the other's barrier
//    drains its staging vmcnt.
// Per branch: 16 nb x 16 kb = 256 blocks; fused = 512 = 2/CU.
__global__ __launch_bounds__(256, 2) void gemm2_k(const float* __restrict__ A1,
                                                  const float* __restrict__ W1,
                                                  float* __restrict__ Y1,
                                                  const float* __restrict__ A2,
                                                  const float* __restrict__ W2,
                                                  float* __restrict__ Y2,
                                                  int half) {
    __shared__ float Alds[NN * KC];        // 14336 B
    __shared__ float Wlds[2][2048 * 4];    // 2 x 32768 B (2048 granules each)
    int bx = blockIdx.x;
    const float* A = A1; const float* W = W1; float* Y = Y1;
    if (bx >= half) { A = A2; W = W2; Y = Y2; bx -= half; }
    const int kb = bx & (KB - 1);     // k chunk (256 wide)
    const int nb = bx >> 4;           // 16 row-blocks of 256
    const int tid = threadIdx.x;      // == row within block
    const int k0  = kb * KC;
    const int brow0 = nb * 256;

    // ---- stage A chunk: 896 granules (row = p>>6, col = (p&63)*4) ----
#pragma unroll
    for (int i = 0; i < 4; ++i) {
        int p = i * 256 + tid;
        if (p < 896)
            gload16(A + (p >> 6) * F + k0 + (p & 63) * 4, &Alds[p * 4]);
    }
    // ---- stage W tile 0 (pre-swizzled source, linear LDS dest) ----
#pragma unroll
    for (int i = 0; i < 8; ++i) {
        int p = i * 256 + tid;             // granule: row = p>>3, slot = p&7
        gload16(W + (size_t)(brow0 + (p >> 3)) * F + k0
                  + (((p & 7) ^ ((p >> 3) & 7)) * 4),
                &Wlds[0][p * 4]);
    }
    __syncthreads();                       // vmcnt(0): A + tile0 ready

    float acc[NN];
#pragma unroll
    for (int m = 0; m < NN; ++m) acc[m] = 0.f;

    const int rsw = tid & 7;               // row&7 for read-side swizzle

    for (int t = 0; t < NT; ++t) {
        const int cur = t & 1;
        if (t + 1 < NT) {                  // stage next tile async
            const int kofs = k0 + (t + 1) * KT;
#pragma unroll
            for (int i = 0; i < 8; ++i) {
                int p = i * 256 + tid;
                gload16(W + (size_t)(brow0 + (p >> 3)) * F + kofs
                          + (((p & 7) ^ ((p >> 3) & 7)) * 4),
                        &Wlds[cur ^ 1][p * 4]);
            }
        }
        // compute tile t: 8 ksteps, lane owns row tid
#pragma unroll
        for (int ks = 0; ks < 8; ++ks) {
            float4 wq = *(const float4*)&Wlds[cur][(tid * 8 + (ks ^ rsw)) * 4];
#pragma unroll
            for (int m = 0; m < NN; ++m) {
                float4 aq = *(const float4*)&Alds[m * KC + t * KT + ks * 4];
                acc[m] += wq.x * aq.x + wq.y * aq.y + wq.z * aq.z + wq.w * aq.w;
            }
        }
        if (t + 1 < NT) __syncthreads();   // drain: next tile staged
    }

    // coalesced stores: per m, 256 threads -> 256 consecutive rows
#pragma unroll
    for (int m = 0; m < NN; ++m)
        Y[kb * YPART + m * F + brow0 + tid] = acc[m];
}

// ---------------- final: h1 edge expansion + h2 tiny GEMV ----------------
__global__ __launch_bounds__(256) void final_k(const float* __restrict__ Ypa5,
                                               const float* __restrict__ ba5,
                                               const float* __restrict__ Av2,
                                               const float* __restrict__ Wv5,
                                               const float* __restrict__ bv5,
                                               float* __restrict__ out) {
    __shared__ float red[NN][257];
    if (blockIdx.x < 176) {
        int idx4 = (blockIdx.x * 256 + threadIdx.x) * 4;  // 44*4096 elements
        int e = idx4 >> 12, f = idx4 & 4095;
        int se = SRC[e], de = DST[e];
        float4 ys = make_float4(0.f, 0.f, 0.f, 0.f);
        float4 yd = make_float4(0.f, 0.f, 0.f, 0.f);
#pragma unroll
        for (int kb = 0; kb < KB; ++kb) {
            float4 s = *(const float4*)(Ypa5 + kb * YPART + se * F + f);
            float4 d = *(const float4*)(Ypa5 + kb * YPART + de * F + f);
            ys.x += s.x; ys.y += s.y; ys.z += s.z; ys.w += s.w;
            yd.x += d.x; yd.y += d.y; yd.z += d.z; yd.w += d.w;
        }
        float4 bb = *(const float4*)(ba5 + f);
        float4 o;
        o.x = 0.5f * (ys.x + yd.x) + bb.x;
        o.y = 0.5f * (ys.y + yd.y) + bb.y;
        o.z = 0.5f * (ys.z + yd.z) + bb.z;
        o.w = 0.5f * (ys.w + yd.w) + bb.w;
        *(float4*)(out + idx4) = o;
    } else {
        // y[n] = dot(Av2[n], Wv5); h2[e] = 0.5*(y[src]+y[dst]) + bv5
        int t = threadIdx.x;
        float acc[NN];
#pragma unroll
        for (int m = 0; m < NN; ++m) acc[m] = 0.f;
        for (int f = t; f < F; f += 256) {
            float wv = Wv5[f];
#pragma unroll
            for (int m = 0; m < NN; ++m) acc[m] += Av2[m * F + f] * wv;
        }
#pragma unroll
        for (int m = 0; m < NN; ++m) red[m][t] = acc[m];
        __syncthreads();
        for (int s = 128; s > 0; s >>= 1) {
            if (t < s) {
#pragma unroll
                for (int m = 0; m < NN; ++m) red[m][t] += red[m][t + s];
            }
            __syncthreads();
        }
        if (t < NE) {
            float ys = red[SRC[t]][0], yd = red[DST[t]][0];
            out[H1SZ + t] = 0.5f * (ys + yd) + bv5[0];
        }
    }
}

extern "C" void kernel_launch(void* const* d_in, const int* in_sizes, int n_in,
                              void* d_out, int out_size, void* d_ws, size_t ws_size,
                              hipStream_t stream) {
    const float* x   = (const float*)d_in[0];
    const float* Wa1 = (const float*)d_in[3];
    const float* ba1 = (const float*)d_in[4];
    const float* Wa2 = (const float*)d_in[5];
    const float* ba2 = (const float*)d_in[6];
    const float* Wa5 = (const float*)d_in[7];
    const float* ba5 = (const float*)d_in[8];
    const float* Wv1 = (const float*)d_in[9];
    const float* bv1 = (const float*)d_in[10];
    const float* Wv2 = (const float*)d_in[11];
    const float* bv2 = (const float*)d_in[12];
    const float* Wv5 = (const float*)d_in[13];
    const float* bv5 = (const float*)d_in[14];
    float* out = (float*)d_out;

    float* ws  = (float*)d_ws;
    float* Ax  = ws;                   // 57344
    float* Aa  = ws + 57344;           // 57344
    float* Av  = ws + 114688;          // 57344
    float* Ypa = ws + 172032;          // KB*57344 = 917504
    float* Ypv = ws + 1089536;         // KB*57344 = 917504 (total ~8.03 MB)

    prep_x_k<<<16,  256, 0, stream>>>(x, Ax);
    gemm2_k <<<512, 256, 0, stream>>>(Ax, Wa1, Ypa, Ax, Wv1, Ypv, 256);
    prep2_k <<<32,  256, 0, stream>>>(Ypa, ba1, Aa, Ypv, bv1, Av);
    gemm2_k <<<512, 256, 0, stream>>>(Aa, Wa2, Ypa, Av, Wv2, Ypv, 256);
    prep2_k <<<32,  256, 0, stream>>>(Ypa, ba2, Aa, Ypv, bv2, Av);
    gemm2_k <<<256, 256, 0, stream>>>(Aa, Wa5, Ypa, Aa, Wa5, Ypa, 256);
    final_k <<<177, 256, 0, stream>>>(Ypa, ba5, Av, Wv5, bv5, out);
}